// Round 1
// baseline (1202.628 us; speedup 1.0000x reference)
//
#include <hip/hip_runtime.h>

#define CRF_B 512
#define CRF_T 2048
#define CRF_K 32
#define CRF_Q (CRF_T / 4)   // 512 packed-bp dwords per batch per column

// Inner i-reduction over this half's 16 candidates.
// ds_swizzle BitMode pattern (or_mask = KK): every lane in each 32-lane group
// reads lane KK of its group. Group 0 (lanes 0-31, lane j holds state[j]) gets
// state[KK]; group 1 (lane 32+j holds state[(j+16)&31]) gets state[16+KK].
// Strict '>' keeps the FIRST max index within the (ascending-i) half.
template<int KK>
__device__ __forceinline__ void kloop(float state, const float (&tr)[16],
                                      float& best, int& bidx) {
    if constexpr (KK < 16) {
        int sb = __builtin_amdgcn_ds_swizzle(__float_as_int(state), (KK << 5));
        float cand = __int_as_float(sb) + tr[KK];
        if (cand > best) { best = cand; bidx = KK; }
        kloop<KK + 1>(state, tr, best, bidx);
    }
}

__global__ __launch_bounds__(64, 1) void crf_fused(
    const float* __restrict__ pot,    // [B,T,K]
    const float* __restrict__ trans,  // [K,K]
    float* __restrict__ out,          // [B,T,K] one-hot fp32
    unsigned int* __restrict__ bp)    // ws: [B, Q, K] packed backpointers
{
    const int b = blockIdx.x;
    const int l = threadIdx.x;
    const int h = l >> 5;                 // which 16-wide i-range this half owns
    const int jv = (l + (h << 4)) & 31;   // state index this lane carries (shifted in half 1)

    // tr[k] = trans[h*16 + k][jv]  (this lane's column slice for its i-range)
    float tr[16];
#pragma unroll
    for (int k = 0; k < 16; ++k) tr[k] = trans[((h << 4) + k) * CRF_K + jv];

    const float* potb = pot + (size_t)b * (CRF_T * CRF_K);
    unsigned int* bpb = bp + (size_t)b * (CRF_Q * CRF_K);
    float* outb = out + (size_t)b * (CRF_T * CRF_K);

    // partner lane: same jv, other half
    const int partner = ((l + 16) & 31) | ((l & 32) ^ 32);

    float state = potb[jv];                 // t = 0
    float pv_next = potb[CRF_K + jv];       // prefetch pot[t=1]

    // ---------------- forward pass ----------------
    unsigned int bpack = 0;

    auto step = [&](int t, float pv) -> void {
        float best = -__builtin_inff(); int bidx = 0;
        kloop<0>(state, tr, best, bidx);
        int my_i = bidx + (h << 4);
        float rv = __shfl(best, partner, 64);
        int   ri = __shfl(my_i, partner, 64);
        // first-index tie rule: half 0 (i in [0,16)) wins ties
        bool take = (rv > best) || ((rv == best) && (h == 1));
        float wv = take ? rv : best;
        int   wi = take ? ri : my_i;
        state = wv + pv;
        bpack |= ((unsigned int)wi) << (8 * (t & 3));
    };

    // q = 0 : t = 1..3 (byte 0 unused; t=0 has no backpointer)
#pragma unroll
    for (int s = 1; s < 4; ++s) {
        float pv = pv_next;
        pv_next = potb[(s + 1) * CRF_K + jv];
        step(s, pv);
    }
    bpb[jv] = bpack;   // both halves store identical values (benign dup)

    for (int q = 1; q < CRF_Q; ++q) {
        bpack = 0;
#pragma unroll
        for (int s = 0; s < 4; ++s) {
            const int t = q * 4 + s;
            float pv = pv_next;
            int tn = t + 1; if (tn > CRF_T - 1) tn = CRF_T - 1;  // clamp final prefetch
            pv_next = potb[tn * CRF_K + jv];
            step(t, pv);
        }
        bpb[q * CRF_K + jv] = bpack;
    }

    // ---------------- last tag (argmax over final state, first-index ties) ----------------
    __shared__ float fs[CRF_K];
    if (l < CRF_K) fs[l] = state;      // lanes 0-31 hold state[j] at lane j
    __syncthreads();
    int bt = 0; float bv = fs[0];
#pragma unroll
    for (int j = 1; j < CRF_K; ++j) {
        float v = fs[j];
        if (v > bv) { bv = v; bt = j; }
    }
    int stag = __builtin_amdgcn_readfirstlane(bt);

    const int c = l & 31;
    // one-hot row for t = T-1 (all 64 lanes; halves write identical 128B row)
    outb[(CRF_T - 1) * CRF_K + c] = (c == stag) ? 1.0f : 0.0f;

    __threadfence();   // make own bp stores visible before read-back

    // ---------------- backtrack: lane c holds COLUMN c of bp ----------------
    // Walk step: tag_{t-1} = byte (t&3) of readlane(col[(t>>2)-q0], tag)
    for (int q0 = CRF_Q - 16; q0 >= 0; q0 -= 16) {
        unsigned int col[16];
#pragma unroll
        for (int r = 0; r < 16; ++r) col[r] = bpb[(q0 + r) * CRF_K + c];
#pragma unroll
        for (int r = 15; r >= 0; --r) {
#pragma unroll
            for (int bi = 3; bi >= 0; --bi) {
                const int t = (q0 + r) * 4 + bi;
                if (t == 0) continue;   // only q0==0, r==0, bi==0
                unsigned int dw = (unsigned int)__builtin_amdgcn_readlane((int)col[r], stag);
                stag = (int)((dw >> (8 * bi)) & 255u);
                outb[(size_t)(t - 1) * CRF_K + c] = (c == stag) ? 1.0f : 0.0f;
            }
        }
    }
}

extern "C" void kernel_launch(void* const* d_in, const int* in_sizes, int n_in,
                              void* d_out, int out_size, void* d_ws, size_t ws_size,
                              hipStream_t stream) {
    const float* pot   = (const float*)d_in[0];   // inputs [512,2048,32] fp32
    const float* trans = (const float*)d_in[1];   // transitions [32,32] fp32
    float* out = (float*)d_out;
    unsigned int* bp = (unsigned int*)d_ws;       // needs 33,554,432 B

    crf_fused<<<dim3(CRF_B), dim3(64), 0, stream>>>(pot, trans, out, bp);
}

// Round 2
// 937.678 us; speedup vs baseline: 1.2826x; 1.2826x over previous
//
#include <hip/hip_runtime.h>

#define CRF_B 512
#define CRF_T 2048
#define CRF_K 32
#define CRF_Q (CRF_T / 4)   // 512 packed-bp dwords per batch per column

// One tournament level: reduce 2N entries (contiguous pairs) to N.
// "right strictly greater" => left (lower index) wins ties => first-index argmax.
template<int N>
__device__ __forceinline__ void tlevel(float (&val)[CRF_K], int (&idx)[CRF_K]) {
#pragma unroll
    for (int k = 0; k < N; ++k) {
        bool t = val[2 * k + 1] > val[2 * k];
        val[k] = t ? val[2 * k + 1] : val[2 * k];
        idx[k] = t ? idx[2 * k + 1] : idx[2 * k];
    }
}

__global__ __launch_bounds__(64, 1) void crf_fused(
    const float* __restrict__ pot,    // [B,T,K]
    const float* __restrict__ trans,  // [K,K]
    float* __restrict__ out,          // [B,T,K] one-hot fp32
    unsigned int* __restrict__ bp)    // ws: [B, Q, K] packed backpointers
{
    const int b = blockIdx.x;
    const int l = threadIdx.x;
    const int j = l & 31;             // upper half duplicates lower (benign)

    // lane j's column of transitions: tr[i] = trans[i][j]
    float tr[CRF_K];
#pragma unroll
    for (int i = 0; i < CRF_K; ++i) tr[i] = trans[i * CRF_K + j];

    const float* potb = pot + (size_t)b * (CRF_T * CRF_K);
    unsigned int* bpb = bp + (size_t)b * (CRF_Q * CRF_K);
    float* outb = out + (size_t)b * (CRF_T * CRF_K);

    float vstate = potb[j];           // t = 0
    // wave-uniform state copies (SGPRs via readlane — no DS on the hot path)
    float s[CRF_K];
#pragma unroll
    for (int i = 0; i < CRF_K; ++i)
        s[i] = __int_as_float(__builtin_amdgcn_readlane(__float_as_int(vstate), i));

    // potential double-buffer: cur = this group's pot rows, nxt = next group's
    float cur[4], nxt[4];
#pragma unroll
    for (int t = 1; t < 4; ++t) cur[t] = potb[t * CRF_K + j];

    for (int q = 0; q < CRF_Q; ++q) {
        // prefetch next group's potentials (~1300 cyc lead; clamped re-load at end)
        {
            const int tb = (q + 1) * 4;
#pragma unroll
            for (int sx = 0; sx < 4; ++sx) {
                int t = tb + sx; if (t > CRF_T - 1) t = CRF_T - 1;
                nxt[sx] = potb[t * CRF_K + j];
            }
        }
        unsigned int bpack = 0;
#pragma unroll
        for (int sx = 0; sx < 4; ++sx) {
            if (q == 0 && sx == 0) continue;   // t=0 has no backpointer
            float val[CRF_K]; int idx[CRF_K];
#pragma unroll
            for (int i = 0; i < CRF_K; ++i) { val[i] = s[i] + tr[i]; idx[i] = i; }
            tlevel<16>(val, idx);
            tlevel<8>(val, idx);
            tlevel<4>(val, idx);
            tlevel<2>(val, idx);
            tlevel<1>(val, idx);
            vstate = val[0] + cur[sx];
            bpack |= ((unsigned int)idx[0]) << (8 * sx);
#pragma unroll
            for (int i = 0; i < CRF_K; ++i)
                s[i] = __int_as_float(__builtin_amdgcn_readlane(__float_as_int(vstate), i));
        }
        bpb[q * CRF_K + j] = bpack;   // halves store identical values (benign dup)
#pragma unroll
        for (int sx = 0; sx < 4; ++sx) cur[sx] = nxt[sx];
    }

    // ---------------- last tag (argmax over final state, first-index ties) ----------------
    __shared__ float fs[CRF_K];
    if (l < CRF_K) fs[l] = vstate;    // lanes 0-31 hold state[j] at lane j
    __syncthreads();
    int bt = 0; float bv = fs[0];
#pragma unroll
    for (int jj = 1; jj < CRF_K; ++jj) {
        float v = fs[jj];
        if (v > bv) { bv = v; bt = jj; }
    }
    int stag = __builtin_amdgcn_readfirstlane(bt);

    const int c = l & 31;
    // one-hot row for t = T-1 (halves write identical 128B row)
    outb[(CRF_T - 1) * CRF_K + c] = (c == stag) ? 1.0f : 0.0f;

    __threadfence();   // make own bp stores visible before read-back

    // ---------------- backtrack: lane c holds COLUMN c of bp ----------------
    for (int q0 = CRF_Q - 16; q0 >= 0; q0 -= 16) {
        unsigned int col[16];
#pragma unroll
        for (int r = 0; r < 16; ++r) col[r] = bpb[(q0 + r) * CRF_K + c];
#pragma unroll
        for (int r = 15; r >= 0; --r) {
#pragma unroll
            for (int bi = 3; bi >= 0; --bi) {
                const int t = (q0 + r) * 4 + bi;
                if (t == 0) continue;   // only q0==0, r==0, bi==0
                unsigned int dw = (unsigned int)__builtin_amdgcn_readlane((int)col[r], stag);
                stag = (int)((dw >> (8 * bi)) & 255u);
                outb[(size_t)(t - 1) * CRF_K + c] = (c == stag) ? 1.0f : 0.0f;
            }
        }
    }
}

extern "C" void kernel_launch(void* const* d_in, const int* in_sizes, int n_in,
                              void* d_out, int out_size, void* d_ws, size_t ws_size,
                              hipStream_t stream) {
    const float* pot   = (const float*)d_in[0];   // inputs [512,2048,32] fp32
    const float* trans = (const float*)d_in[1];   // transitions [32,32] fp32
    float* out = (float*)d_out;
    unsigned int* bp = (unsigned int*)d_ws;       // needs 33,554,432 B

    crf_fused<<<dim3(CRF_B), dim3(64), 0, stream>>>(pot, trans, out, bp);
}